// Round 2
// baseline (2663.672 us; speedup 1.0000x reference)
//
#include <hip/hip_runtime.h>
#include <hip/hip_bf16.h>

#define BATCH 2048
#define LSIG 2048
#define TSTEPS 512
#define CH 32            // LSTM steps per chunk
#define NCHUNK (TSTEPS / CH)

__device__ __forceinline__ float sigf(float x) {
    return __fdividef(1.f, 1.f + __expf(-x));
}
__device__ __forceinline__ float tanhfast(float x) {
    return 1.f - __fdividef(2.f, __expf(2.f * x) + 1.f);
}

// One 64-lane wave per (sample, branch): conv1(1->16,k3,p1) + relu + maxpool2
// -> conv2(16->32,k3,p1) + relu + maxpool2 -> LSTM(32->32, T=512) -> h_n[32]
__global__ __launch_bounds__(64, 2) void branch_kernel(
    const float* __restrict__ x0, const float* __restrict__ x1,
    const float* __restrict__ x2, const float* __restrict__ x3,
    const float* __restrict__ c1w, const float* __restrict__ c1b,
    const float* __restrict__ c2w, const float* __restrict__ c2b,
    const float* __restrict__ wih, const float* __restrict__ whh,
    const float* __restrict__ bih, const float* __restrict__ bhh,
    float* __restrict__ feats)
{
    const int s    = blockIdx.x;
    const int br   = blockIdx.y;
    const int lane = threadIdx.x;
    const float* xg = (br == 0) ? x0 : (br == 1) ? x1 : (br == 2) ? x2 : x3;

    __shared__ float xs[LSIG + 2];          // zero-padded input signal
    __shared__ float p1buf[2 * CH + 2][16]; // pooled1 window for one chunk
    __shared__ float seqb[CH][32];          // LSTM inputs for one chunk
    __shared__ float hbuf[32];              // hidden state broadcast

    // ---- load x (zero-padded at both ends) ----
    for (int i = lane; i < LSIG + 2; i += 64) {
        float v = 0.f;
        if (i >= 1 && i <= LSIG) v = xg[(size_t)s * LSIG + (i - 1)];
        xs[i] = v;
    }

    // ---- per-lane weights in registers ----
    const int ci1 = lane & 15;                  // conv1 out-channel for phase A
    const float w10 = c1w[br * 48 + ci1 * 3 + 0];
    const float w11 = c1w[br * 48 + ci1 * 3 + 1];
    const float w12 = c1w[br * 48 + ci1 * 3 + 2];
    const float b1v = c1b[br * 16 + ci1];

    const int co = lane & 31;                   // conv2 out-channel for phase B
    float w2r[48];
    {
        const float4* p = (const float4*)(c2w + br * 32 * 48 + co * 48);
        #pragma unroll
        for (int i = 0; i < 12; ++i) ((float4*)w2r)[i] = p[i];
    }
    const float b2v = c2b[br * 32 + co];

    // LSTM: lane j owns gate rows j and j+64 (torch order i,f,g,o)
    float wi0[32], wi1[32], wh0[32], wh1[32];
    {
        const float4* pi0 = (const float4*)(wih + (size_t)(br * 128 + lane) * 32);
        const float4* pi1 = (const float4*)(wih + (size_t)(br * 128 + lane + 64) * 32);
        const float4* ph0 = (const float4*)(whh + (size_t)(br * 128 + lane) * 32);
        const float4* ph1 = (const float4*)(whh + (size_t)(br * 128 + lane + 64) * 32);
        #pragma unroll
        for (int i = 0; i < 8; ++i) {
            ((float4*)wi0)[i] = pi0[i];
            ((float4*)wi1)[i] = pi1[i];
            ((float4*)wh0)[i] = ph0[i];
            ((float4*)wh1)[i] = ph1[i];
        }
    }
    const float bs0 = bih[br * 128 + lane]      + bhh[br * 128 + lane];
    const float bs1 = bih[br * 128 + lane + 64] + bhh[br * 128 + lane + 64];

    if (lane < 32) hbuf[lane] = 0.f;
    float c_state = 0.f;
    __syncthreads();

    const int tl_b = lane >> 5;   // phase-B row split

    for (int chk = 0; chk < NCHUNK; ++chk) {
        const int t0 = chk * CH;

        // ---- phase A: pooled1 window [2*t0-1, 2*t0+2*CH+1), 66 x 16 ----
        #pragma unroll 1
        for (int it = 0; it < 17; ++it) {
            int idx = it * 64 + lane;
            if (idx < (2 * CH + 2) * 16) {
                int pl  = idx >> 4;
                int p1g = 2 * t0 - 1 + pl;
                float v = 0.f;
                if (p1g >= 0 && p1g < LSIG / 2) {
                    int j = 2 * p1g;  // xs[j+k] == x[j-1+k] (zero padded)
                    float a0 = fmaf(xs[j + 2], w12, fmaf(xs[j + 1], w11, fmaf(xs[j + 0], w10, b1v)));
                    float a1 = fmaf(xs[j + 3], w12, fmaf(xs[j + 2], w11, fmaf(xs[j + 1], w10, b1v)));
                    v = fmaxf(fmaxf(a0, a1), 0.f);
                }
                p1buf[pl][idx & 15] = v;
            }
        }
        __syncthreads();

        // ---- phase B: conv2 + relu + maxpool2 -> seqb[CH][32] ----
        #pragma unroll 1
        for (int it = 0; it < (CH * 32) / 64; ++it) {  // 16 iters
            int tl = it * 2 + tl_b;
            float acc0 = b2v, acc1 = b2v;
            #pragma unroll
            for (int r = 0; r < 4; ++r) {
                float row[16];
                const float4* rp = (const float4*)(&p1buf[2 * tl + r][0]);
                #pragma unroll
                for (int u = 0; u < 4; ++u) ((float4*)row)[u] = rp[u];
                if (r < 3) {
                    #pragma unroll
                    for (int cc = 0; cc < 16; ++cc)
                        acc0 = fmaf(row[cc], w2r[cc * 3 + r], acc0);
                }
                if (r >= 1) {
                    #pragma unroll
                    for (int cc = 0; cc < 16; ++cc)
                        acc1 = fmaf(row[cc], w2r[cc * 3 + (r - 1)], acc1);
                }
            }
            seqb[tl][co] = fmaxf(fmaxf(acc0, acc1), 0.f);
        }
        __syncthreads();

        // ---- phase C: LSTM over CH steps ----
        #pragma unroll 1
        for (int tl = 0; tl < CH; ++tl) {
            float g0 = bs0, g1 = bs1;
            #pragma unroll
            for (int kk = 0; kk < 8; ++kk) {
                const float4 xv = *(const float4*)(&seqb[tl][kk * 4]);
                const float4 hv = *(const float4*)(&hbuf[kk * 4]);
                g0 = fmaf(xv.x, wi0[4 * kk + 0], g0);
                g0 = fmaf(xv.y, wi0[4 * kk + 1], g0);
                g0 = fmaf(xv.z, wi0[4 * kk + 2], g0);
                g0 = fmaf(xv.w, wi0[4 * kk + 3], g0);
                g1 = fmaf(xv.x, wi1[4 * kk + 0], g1);
                g1 = fmaf(xv.y, wi1[4 * kk + 1], g1);
                g1 = fmaf(xv.z, wi1[4 * kk + 2], g1);
                g1 = fmaf(xv.w, wi1[4 * kk + 3], g1);
                g0 = fmaf(hv.x, wh0[4 * kk + 0], g0);
                g0 = fmaf(hv.y, wh0[4 * kk + 1], g0);
                g0 = fmaf(hv.z, wh0[4 * kk + 2], g0);
                g0 = fmaf(hv.w, wh0[4 * kk + 3], g0);
                g1 = fmaf(hv.x, wh1[4 * kk + 0], g1);
                g1 = fmaf(hv.y, wh1[4 * kk + 1], g1);
                g1 = fmaf(hv.z, wh1[4 * kk + 2], g1);
                g1 = fmaf(hv.w, wh1[4 * kk + 3], g1);
            }
            // lane m<32 holds i_m,g_m ; lane 32+m holds f_m,o_m
            float a0 = sigf(g0);                         // sig(i) or sig(f)
            float th = tanhfast(g1);
            float sg = sigf(g1);
            float a1 = (lane < 32) ? th : sg;            // tanh(g) or sig(o)
            float fa = __shfl_xor(a0, 32);               // sig(f) for lanes<32
            float oa = __shfl_xor(a1, 32);               // sig(o) for lanes<32
            if (lane < 32) {
                c_state = fmaf(fa, c_state, a0 * a1);
                hbuf[lane] = oa * tanhfast(c_state);
            }
            __syncthreads();
        }
    }

    if (lane < 32)
        feats[((size_t)br * BATCH + s) * 32 + lane] = hbuf[lane];
}

// ---------------- tail: bottleneck + 8-qubit statevector + classifier -------

__device__ __forceinline__ void apply1q(float2* psi, int lane, int q,
                                        float2 g00, float2 g01,
                                        float2 g10, float2 g11)
{
    const int shift = 7 - q;
    const int right = 1 << shift;
    #pragma unroll
    for (int pp = 0; pp < 2; ++pp) {
        int p  = lane + 64 * pp;
        int l  = p >> shift;
        int r  = p & (right - 1);
        int i0 = (l << (shift + 1)) + r;
        int i1 = i0 + right;
        float2 a = psi[i0], b = psi[i1];
        float2 n0 = make_float2(g00.x * a.x - g00.y * a.y + g01.x * b.x - g01.y * b.y,
                                g00.x * a.y + g00.y * a.x + g01.x * b.y + g01.y * b.x);
        float2 n1 = make_float2(g10.x * a.x - g10.y * a.y + g11.x * b.x - g11.y * b.y,
                                g10.x * a.y + g10.y * a.x + g11.x * b.y + g11.y * b.x);
        psi[i0] = n0;
        psi[i1] = n1;
    }
    __syncthreads();
}

__global__ __launch_bounds__(64) void tail_kernel(
    const float* __restrict__ feats, const float* __restrict__ bw,
    const float* __restrict__ bb, const float* __restrict__ qw,
    const float* __restrict__ cw, const float* __restrict__ cb,
    float* __restrict__ out)
{
    const int s    = blockIdx.x;
    const int lane = threadIdx.x;

    __shared__ float comb[128];
    __shared__ float2 psi[256];
    __shared__ float ang[8];

    // combined[br*32+k] = feats[br][s][k]
    comb[lane]      = feats[(size_t)(lane >> 5) * (BATCH * 32) + (size_t)s * 32 + (lane & 31)];
    comb[lane + 64] = feats[(size_t)((lane + 64) >> 5) * (BATCH * 32) + (size_t)s * 32 + (lane & 31)];
    __syncthreads();

    // bottleneck: compressed[q] = tanh(comb . bott_w[q] + bott_b[q]); 8 lanes/q
    {
        int q = lane >> 3, k0 = lane & 7;
        float p = 0.f;
        #pragma unroll
        for (int i = 0; i < 16; ++i) {
            int k = k0 + 8 * i;
            p = fmaf(comb[k], bw[q * 128 + k], p);
        }
        p += __shfl_xor(p, 4);
        p += __shfl_xor(p, 2);
        p += __shfl_xor(p, 1);
        if (k0 == 0) ang[q] = tanhf(p + bb[q]);
    }
    // init |0...0>
    #pragma unroll
    for (int r = 0; r < 4; ++r) {
        int idx = lane + 64 * r;
        psi[idx] = make_float2(idx == 0 ? 1.f : 0.f, 0.f);
    }
    __syncthreads();

    const float PI_F = 3.14159265358979323846f;

    // RX embedding (per-sample angles)
    for (int q = 0; q < 8; ++q) {
        float half = ang[q] * PI_F * 0.5f;
        float cv = cosf(half), sv = sinf(half);
        apply1q(psi, lane, q,
                make_float2(cv, 0.f), make_float2(0.f, -sv),
                make_float2(0.f, -sv), make_float2(cv, 0.f));
    }

    // entangling layers: Rot = RZ(omega) RY(theta) RZ(phi), then CNOT ring
    for (int l = 0; l < 3; ++l) {
        for (int q = 0; q < 8; ++q) {
            float phi = qw[(l * 8 + q) * 3 + 0];
            float th  = qw[(l * 8 + q) * 3 + 1];
            float om  = qw[(l * 8 + q) * 3 + 2];
            float ct = cosf(0.5f * th), st = sinf(0.5f * th);
            float A = 0.5f * (phi + om), D = 0.5f * (phi - om);
            float cA = cosf(A), sA = sinf(A), cD = cosf(D), sD = sinf(D);
            apply1q(psi, lane, q,
                    make_float2(ct * cA, -ct * sA), make_float2(-st * cD, -st * sD),
                    make_float2(st * cD, -st * sD), make_float2(ct * cA,  ct * sA));
        }
        int stride = l + 1;
        for (int q = 0; q + stride < 8; ++q) {
            int cbit = 1 << (7 - q);
            int tbit = 1 << (7 - (q + stride));
            #pragma unroll
            for (int r = 0; r < 4; ++r) {
                int idx = lane + 64 * r;
                if ((idx & cbit) && !(idx & tbit)) {
                    int j = idx | tbit;
                    float2 tmp = psi[idx];
                    psi[idx] = psi[j];
                    psi[j] = tmp;
                }
            }
            __syncthreads();
        }
    }

    // <Z_i> then classifier
    float z[8];
    #pragma unroll
    for (int q = 0; q < 8; ++q) z[q] = 0.f;
    #pragma unroll
    for (int r = 0; r < 4; ++r) {
        int idx = lane + 64 * r;
        float2 a = psi[idx];
        float pr = a.x * a.x + a.y * a.y;
        #pragma unroll
        for (int q = 0; q < 8; ++q)
            z[q] += (idx & (1 << (7 - q))) ? -pr : pr;
    }
    #pragma unroll
    for (int q = 0; q < 8; ++q) {
        #pragma unroll
        for (int off = 32; off; off >>= 1) z[q] += __shfl_xor(z[q], off);
    }
    if (lane == 0) {
        #pragma unroll
        for (int c = 0; c < 3; ++c) {
            float acc = cb[c];
            #pragma unroll
            for (int q = 0; q < 8; ++q) acc = fmaf(z[q], cw[c * 8 + q], acc);
            out[s * 3 + c] = acc;
        }
    }
}

extern "C" void kernel_launch(void* const* d_in, const int* in_sizes, int n_in,
                              void* d_out, int out_size, void* d_ws, size_t ws_size,
                              hipStream_t stream)
{
    (void)in_sizes; (void)n_in; (void)out_size; (void)ws_size;
    const float* x0  = (const float*)d_in[0];
    const float* x1  = (const float*)d_in[1];
    const float* x2  = (const float*)d_in[2];
    const float* x3  = (const float*)d_in[3];
    const float* c1w = (const float*)d_in[4];
    const float* c1b = (const float*)d_in[5];
    const float* c2w = (const float*)d_in[6];
    const float* c2b = (const float*)d_in[7];
    const float* wih = (const float*)d_in[8];
    const float* whh = (const float*)d_in[9];
    const float* bih = (const float*)d_in[10];
    const float* bhh = (const float*)d_in[11];
    const float* bw  = (const float*)d_in[12];
    const float* bb  = (const float*)d_in[13];
    const float* qw  = (const float*)d_in[14];
    const float* cw  = (const float*)d_in[15];
    const float* cb  = (const float*)d_in[16];

    float* feats = (float*)d_ws;  // [4][BATCH][32] f32 = 1 MB

    branch_kernel<<<dim3(BATCH, 4), 64, 0, stream>>>(
        x0, x1, x2, x3, c1w, c1b, c2w, c2b, wih, whh, bih, bhh, feats);
    tail_kernel<<<BATCH, 64, 0, stream>>>(
        feats, bw, bb, qw, cw, cb, (float*)d_out);
}